// Round 8
// baseline (286.127 us; speedup 1.0000x reference)
//
#include <hip/hip_runtime.h>

// YOLO layer: (64, 30, 152, 152) fp32 -> (64, 3*152*152, 10) fp32
// Memory-bound transpose + elementwise. Traffic floor ~355MB. Score includes
// ~218us of harness fill dispatches; kernel portion = score - ~218us.
// R3: 2 pos/thread, 20KB LDS, plain loads + NT stores -> ~84us kernel.
// R5: NT dwordx2 loads + NT stores -> kernel ~66us (5.4 TB/s), score 282.3. BEST.
// R6: 4 pos/thread dwordx4 + 40KB LDS -> REGRESSED (dirty A/B: halved occupancy).
// R7: NT loads + plain stores -> REGRESSED (288.2). NT both ways optimal.
// R10: R5 revert reproduced 284.1 -> R5 confirmed, noise ~±2us.
// R11 (this round): clean test of the LAST unfalsified hypothesis — the 8B/lane
//     read granule. Raw-stage input into LDS with contiguous dwordx4 loads
//     (16B/lane, copy-class, same width as the 6.29TB/s m13 ceiling bench)
//     at UNCHANGED 20KB LDS / 8 blocks/CU. Pipeline per block:
//       stage 1280 float4 chunks (5/thread, ch-row-major) -> barrier ->
//       b64 reads (2 pos x 10ch) -> compute -> barrier ->
//       transposed b128 writes -> barrier -> coalesced NT writeback.
//     Plane straddle: block's 512-pos window crosses (b,a) planes only at
//     64-pos-aligned offsets (gcd(512,G2)=64) -> 4-pos chunks never split.
//     Pre-commit: positive -> granule was the limiter; null/regress -> revert
//     to R5 and declare roofline.

constexpr int G    = 152;
constexpr int G2   = G * G;        // 23104
constexpr int NA   = 3;
constexpr int NOUT = 10;           // NUM_CLASSES + 7
constexpr int PPB  = 512;          // positions per block
constexpr int TOTAL_POS = 64 * NA * G2;    // 4,435,968
constexpr int NBLOCKS   = TOTAL_POS / PPB; // 8664, exact

typedef float floatx4 __attribute__((ext_vector_type(4)));
typedef float floatx2 __attribute__((ext_vector_type(2)));

__device__ __forceinline__ float fast_sigmoid(float v) {
    return 1.0f / (1.0f + __expf(-v));
}

__global__ __launch_bounds__(256) void yolo_kernel(
    const float* __restrict__ x,
    const int*   __restrict__ img_size_p,
    float*       __restrict__ out)
{
    __shared__ float lds[PPB * NOUT];   // 20 KB: raw [ch][512], then transposed

    const int t = threadIdx.x;
    const int ppos0 = blockIdx.x * PPB;       // global position base
    const int ba0   = ppos0 / G2;
    const int off0  = ppos0 - ba0 * G2;       // multiple of 64
    const int n0    = G2 - off0;              // plane-ba0 positions in window (mult of 64)

    // img_size: 1-element array, int32 per harness rules; hedge for fp32 bits.
    int iv = *img_size_p;
    float img_size = (iv > 0 && iv < (1 << 20)) ? (float)iv : __int_as_float(iv);
    const float stride = img_size / (float)G;   // 8.0

    // ---- raw stage: 1280 chunks, 5/thread; every load is contiguous dwordx4.
    // Chunk c -> channel row ch=c>>7, local pos i=4*(c&127); LDS float4 slot c.
    // Within a wave ch is uniform and pos is lane-contiguous -> 1KB/wave/instr.
    floatx4* l4 = reinterpret_cast<floatx4*>(lds);
#pragma unroll
    for (int r = 0; r < 5; ++r) {
        const int c  = r * 256 + t;
        const int ch = c >> 7;
        const int i  = (c & 127) * 4;
        const bool second = (i >= n0);        // chunk lies in plane ba0+1
        const int  ba  = ba0 + (second ? 1 : 0);
        const int  pos = second ? (i - n0) : (off0 + i);
        const size_t src = (size_t)(ba * NOUT + ch) * G2 + pos;
        l4[c] = __builtin_nontemporal_load(
            reinterpret_cast<const floatx4*>(x + src));
    }
    __syncthreads();

    // ---- per-thread: 2 adjacent positions. p even & G,G2 even -> the pair
    // never straddles a grid row or a plane.
    const int p   = ppos0 + 2 * t;
    const int ba  = p / G2;
    const int rem = p - ba * G2;
    const int y   = rem / G;
    const int x0  = rem - y * G;
    const int a   = ba % NA;

    const float aw[NA] = {12.0f, 19.0f, 40.0f};
    const float ah[NA] = {16.0f, 36.0f, 28.0f};
    const float anchor_w = (aw[a] / stride) * stride;
    const float anchor_h = (ah[a] / stride) * stride;

    // b64 transpose-reads: byte addr ch*2048 + 8t -> 4-way bank aliasing
    // (lanes t, t+16 share a bank) — ~1.6x LDS-cycle cost, LDS has 10x headroom.
    floatx2 q[NOUT];
#pragma unroll
    for (int ch = 0; ch < NOUT; ++ch)
        q[ch] = *reinterpret_cast<const floatx2*>(lds + ch * PPB + 2 * t);

    alignas(16) float buf[2 * NOUT];
#pragma unroll
    for (int j = 0; j < 2; ++j) {
        const float v0 = q[0][j];
        const float v1 = q[1][j];
        const float v2 = q[2][j];
        const float v3 = q[3][j];
        const float v4 = q[4][j];
        const float v5 = q[5][j];
        const float v6 = q[6][j];
        const float v7 = q[7][j];
        const float v8 = q[8][j];
        const float v9 = q[9][j];

        const float bx = fast_sigmoid(v0) * 1.05f - 0.5f * (1.05f - 1.0f);
        const float by = fast_sigmoid(v1) * 1.05f - 0.5f * (1.05f - 1.0f);

        buf[j * NOUT + 0] = (bx + (float)(x0 + j)) * stride;
        buf[j * NOUT + 1] = (by + (float)y) * stride;
        buf[j * NOUT + 2] = __expf(v2) * anchor_w;
        buf[j * NOUT + 3] = __expf(v3) * anchor_h;
        buf[j * NOUT + 4] = v4;
        buf[j * NOUT + 5] = v5;
        buf[j * NOUT + 6] = fast_sigmoid(v6);
        buf[j * NOUT + 7] = fast_sigmoid(v7);
        buf[j * NOUT + 8] = fast_sigmoid(v8);
        buf[j * NOUT + 9] = fast_sigmoid(v9);
    }

    __syncthreads();   // all raw reads complete before overwrite

    // Transposed stage: thread t owns float4-slots [t*5, t*5+5) = its 2
    // positions x 10ch, matching the [pos][ch] output layout.
    const floatx4* b4 = reinterpret_cast<const floatx4*>(buf);
#pragma unroll
    for (int w = 0; w < 5; ++w)
        l4[t * 5 + w] = b4[w];

    __syncthreads();

    // Coalesced writeback: 5 rounds, lane-stride 16B, NT (write-once stream).
    floatx4* dst = reinterpret_cast<floatx4*>(out) + (size_t)blockIdx.x * (256 * 5);
#pragma unroll
    for (int r = 0; r < 5; ++r)
        __builtin_nontemporal_store(l4[r * 256 + t], dst + r * 256 + t);
}

extern "C" void kernel_launch(void* const* d_in, const int* in_sizes, int n_in,
                              void* d_out, int out_size, void* d_ws, size_t ws_size,
                              hipStream_t stream) {
    const float* x = (const float*)d_in[0];
    const int* img_size_p = (const int*)d_in[1];
    float* out = (float*)d_out;

    yolo_kernel<<<NBLOCKS, 256, 0, stream>>>(x, img_size_p, out);
}

// Round 9
// 283.054 us; speedup vs baseline: 1.0109x; 1.0109x over previous
//
#include <hip/hip_runtime.h>

// YOLO layer: (64, 30, 152, 152) fp32 -> (64, 3*152*152, 10) fp32
// Memory-bound transpose + elementwise. Traffic floor ~355MB. Score includes
// ~218us of harness fill dispatches; kernel portion = score - ~218us.
// R1: direct 160B-stride stores -> 117us kernel.
// R3: 2 pos/thread, 20KB LDS, plain loads + NT stores -> ~84us kernel.
// R5: NT dwordx2 loads + NT stores -> kernel ~66us (5.4 TB/s), score 282.3. BEST.
// R6: 4 pos/thread dwordx4 + 40KB LDS -> REGRESSED 287.1 (occupancy halved).
// R7: NT loads + plain stores -> REGRESSED 288.2 (L3 write-allocate loses).
// R10: R5 revert -> 284.1. Confirmed best; noise ~±2us.
// R11: iso-occupancy dwordx4 raw-stage + LDS transpose -> 286.1 (null).
//     Read granule falsified as the limiter.
// R12 (this round): final revert to R5. Every candidate for the ~10us gap to
//     the 6.29TB/s copy ceiling is now falsified (store policy, load width,
//     load granule, bank conflicts 0, occupancy 100%). Remaining gap is the
//     10-concurrent-read-stream cost inherent to the [C][HW]->[HW][C]
//     transpose. This is the measured roofline for this op.

constexpr int G    = 152;
constexpr int G2   = G * G;      // 23104
constexpr int NA   = 3;
constexpr int NOUT = 10;         // NUM_CLASSES + 7
constexpr int P2   = G2 / 2;     // 11552 float2-groups per (b,a) plane

typedef float floatx4 __attribute__((ext_vector_type(4)));
typedef float floatx2 __attribute__((ext_vector_type(2)));

__device__ __forceinline__ float fast_sigmoid(float v) {
    return 1.0f / (1.0f + __expf(-v));
}

// grid = 8664 blocks x 256 threads; each thread owns 2 consecutive positions.
// 8664*256 tiles the 2,217,984 float2-groups exactly -> no bounds guard.
__global__ __launch_bounds__(256) void yolo_kernel(
    const float* __restrict__ x,
    const int*   __restrict__ img_size_p,
    float*       __restrict__ out)
{
    __shared__ float lds[256 * 2 * NOUT];   // 20 KB: 512 positions x 10 ch

    const int t   = threadIdx.x;
    const int idx = blockIdx.x * 256 + t;   // float2-group id

    // img_size: 1-element array, int32 per harness rules; hedge for fp32 bits.
    int iv = *img_size_p;
    float img_size = (iv > 0 && iv < (1 << 20)) ? (float)iv : __int_as_float(iv);
    const float stride = img_size / (float)G;   // 8.0

    const float aw[NA] = {12.0f, 19.0f, 40.0f};
    const float ah[NA] = {16.0f, 36.0f, 28.0f};

    const int pos2 = idx % P2;
    const int ba   = idx / P2;       // b*3 + a
    const int a    = ba % NA;

    const int pos = pos2 * 2;        // G%2==0 -> both positions share a grid row
    const int y   = pos / G;
    const int x0  = pos - y * G;

    // 10 coalesced float2 channel loads (lane stride 8B -> 512B/wave/instr).
    // Nontemporal: input is read-once and exceeds L2/L3; don't retain.
    floatx2 p[NOUT];
    const float* xbase = x + (size_t)ba * (NOUT * G2) + pos;
#pragma unroll
    for (int ch = 0; ch < NOUT; ++ch)
        p[ch] = __builtin_nontemporal_load(
            reinterpret_cast<const floatx2*>(xbase + (size_t)ch * G2));

    const float anchor_w = (aw[a] / stride) * stride;
    const float anchor_h = (ah[a] / stride) * stride;

    alignas(16) float buf[2 * NOUT];
#pragma unroll
    for (int j = 0; j < 2; ++j) {
        const float v0 = p[0][j];
        const float v1 = p[1][j];
        const float v2 = p[2][j];
        const float v3 = p[3][j];
        const float v4 = p[4][j];
        const float v5 = p[5][j];
        const float v6 = p[6][j];
        const float v7 = p[7][j];
        const float v8 = p[8][j];
        const float v9 = p[9][j];

        const float bx = fast_sigmoid(v0) * 1.05f - 0.5f * (1.05f - 1.0f);
        const float by = fast_sigmoid(v1) * 1.05f - 0.5f * (1.05f - 1.0f);

        buf[j * NOUT + 0] = (bx + (float)(x0 + j)) * stride;
        buf[j * NOUT + 1] = (by + (float)y) * stride;
        buf[j * NOUT + 2] = __expf(v2) * anchor_w;
        buf[j * NOUT + 3] = __expf(v3) * anchor_h;
        buf[j * NOUT + 4] = v4;
        buf[j * NOUT + 5] = v5;
        buf[j * NOUT + 6] = fast_sigmoid(v6);
        buf[j * NOUT + 7] = fast_sigmoid(v7);
        buf[j * NOUT + 8] = fast_sigmoid(v8);
        buf[j * NOUT + 9] = fast_sigmoid(v9);
    }

    // Stage to LDS: thread t owns float4-slots [t*5, t*5+5).
    // Start banks (20t)%32 over 8-lane service groups cover all 32 banks ->
    // conflict-free ds_write_b128.
    floatx4* l4 = reinterpret_cast<floatx4*>(lds);
    const floatx4* b4 = reinterpret_cast<const floatx4*>(buf);
#pragma unroll
    for (int w = 0; w < 5; ++w)
        l4[t * 5 + w] = b4[w];

    __syncthreads();

    // Coalesced writeback: 5 rounds, lane i writes 16B at lane-stride 16B.
    // Nontemporal: output is write-once; bypass L2/L3 (R7 measured +4us for
    // letting it allocate).
    floatx4* dst = reinterpret_cast<floatx4*>(out) + (size_t)blockIdx.x * (256 * 5);
#pragma unroll
    for (int r = 0; r < 5; ++r) {
        floatx4 v = l4[r * 256 + t];
        __builtin_nontemporal_store(v, dst + r * 256 + t);
    }
}

extern "C" void kernel_launch(void* const* d_in, const int* in_sizes, int n_in,
                              void* d_out, int out_size, void* d_ws, size_t ws_size,
                              hipStream_t stream) {
    const float* x = (const float*)d_in[0];
    const int* img_size_p = (const int*)d_in[1];
    float* out = (float*)d_out;

    const int total2 = 64 * NA * P2;          // 2,217,984 thread-groups
    const int blocks = total2 / 256;          // 8664, exact
    yolo_kernel<<<blocks, 256, 0, stream>>>(x, img_size_p, out);
}